// Round 1
// 253.443 us; speedup vs baseline: 1.0363x; 1.0363x over previous
//
#include <hip/hip_runtime.h>
#include <stdint.h>
#include <math.h>

// ---------------------------------------------------------------------------
// DFT_12223476924859: STFT via batched real-pair FFT (memory-bound).
//   out0[b,k,t] = Re X_t[k], out1[b,k,t] = Im X_t[k],  X_t = FFT(win*frame_t)
// Two real frames packed per complex 2048-pt FFT. Stockham radix-4 DIF:
// 5 stages (s=1,4,16,64,256) + final radix-2 (twiddle=1) folded into the
// conjugate-symmetric unpack. 6 barriers total.
//
// R1 (this round): LDS bank-conflict elimination.
//  - fft_pairs: SoA float re/im with pad swizzle W(w)=w+(w>>4).
//    Old AoS float2 stage writes were 16-way (s=1,4) / 4-way (s=16)
//    conflicted (group strides = 0 mod 32 banks). Per-stage m-offset in
//    padded space is static: os = s + (s>>4)  (verified no 16-boundary
//    crossings for m*s within any stage).
//  - transpose_out: tile split into two float[64][65] arrays (odd word
//    stride 65 -> conflict-free column reads; was 4-way with float2[.][65]).
//  - interior pairs (p in [1,254]: no reflect) load x/win as float4.
// Harness fills (~105us re-poison) are fixed overhead outside our control.
// ---------------------------------------------------------------------------

#define N_FFT   2048
#define HOP     512
#define BATCH   16
#define LENGTH  262144
#define FRAMES  513
#define OHALF   ((size_t)BATCH * N_FFT * FRAMES)  // 16,809,984
#define KS      1026                      // per-frame float2 stride in scratch
#define PAIRS   257                       // ceil(513/2)

// padded LDS index: 1 pad word per 16 -> breaks 32-bank alignment of the
// stage write strides while keeping stride-1 reads ~2-way (free).
#define WIDX(w) ((w) + ((w) >> 4))
#define LDSN    2176                      // WIDX(2047)=2174, rounded up

__device__ __forceinline__ float2 cmul(float2 a, float2 w) {
    return make_float2(a.x * w.x - a.y * w.y, a.x * w.y + a.y * w.x);
}

// ============================ FFT path =====================================

__global__ void init_tables(float2* __restrict__ tw, float* __restrict__ win) {
    int i = blockIdx.x * 256 + threadIdx.x;   // grid covers 0..2047
    if (i < 2048) {
        double a = -2.0 * M_PI * (double)i / 2048.0;
        tw[i] = make_float2((float)cos(a), (float)sin(a));
        double aw = 2.0 * M_PI * (double)i / 2048.0;
        win[i] = (float)(0.5 - 0.5 * cos(aw));
    }
}

// One block = one pair of frames (2p, 2p+1) of one batch.
// z = wxA + i*wxB; Stockham radix-4, LDS ping-pong (SoA + pad swizzle),
// natural-order output.
__global__ __launch_bounds__(256) void fft_pairs(
    const float* __restrict__ x, const float2* __restrict__ tw,
    const float* __restrict__ win, float2* __restrict__ sc)
{
    __shared__ float sre[2][LDSN];   // ~34.8 KB total (re+im, ping-pong)
    __shared__ float sim[2][LDSN];

    const int tid = threadIdx.x;
    const int p   = blockIdx.x;       // pair index 0..256
    const int b   = blockIdx.y;
    const int fA  = 2 * p;
    const int fB  = 2 * p + 1;
    const bool hasB = (fB < FRAMES);
    const float* xb = x + (size_t)b * LENGTH;

    // ---- load windowed frames ----
    if (p >= 1 && p <= 254) {
        // interior: no reflect on either frame; bases 16B-aligned
        const float4* xA = (const float4*)(xb + fA * HOP - (N_FFT / 2));
        const float4* xB = (const float4*)(xb + fB * HOP - (N_FFT / 2));
        const float4* w4 = (const float4*)win;
        #pragma unroll
        for (int j = 0; j < 2; ++j) {
            int q = tid + 256 * j;            // float4 index, covers 2048 floats
            float4 wv = w4[q];
            float4 va = xA[q];
            float4 vb = xB[q];
            int wn = 4 * q + (q >> 2);        // = WIDX(4q); +0..3 stays in block
            sre[0][wn + 0] = va.x * wv.x;
            sre[0][wn + 1] = va.y * wv.y;
            sre[0][wn + 2] = va.z * wv.z;
            sre[0][wn + 3] = va.w * wv.w;
            sim[0][wn + 0] = vb.x * wv.x;
            sim[0][wn + 1] = vb.y * wv.y;
            sim[0][wn + 2] = vb.z * wv.z;
            sim[0][wn + 3] = vb.w * wv.w;
        }
    } else {
        // boundary pairs (p=0,255,256): reflect padding, scalar path
        #pragma unroll
        for (int j = 0; j < 8; ++j) {
            int n = tid + 256 * j;
            float w = win[n];
            int ja = fA * HOP + n - (N_FFT / 2);
            ja = (ja < 0) ? -ja : ((ja >= LENGTH) ? 2 * LENGTH - 2 - ja : ja);
            float va = xb[ja] * w;
            float vb = 0.f;
            if (hasB) {
                int jb = fB * HOP + n - (N_FFT / 2);
                jb = (jb < 0) ? -jb : ((jb >= LENGTH) ? 2 * LENGTH - 2 - jb : jb);
                vb = xb[jb] * w;
            }
            int wn = WIDX(n);
            sre[0][wn] = va;
            sim[0][wn] = vb;
        }
    }
    __syncthreads();

    // ---- 5 Stockham radix-4 DIF stages: s = 1,4,16,64,256 ----
    // butterfly idx in [0,512): sp = idx & ~(s-1) (= s*p')
    //   a_m = X[idx + m*512];  Z[idx + 3*sp + m*s] = tw[m*sp] * DFT4(a)[m]
    // padded-space read offsets: 512+32=544 per m; write m-step os=s+(s>>4).
    int src = 0;
    #pragma unroll
    for (int ls = 0; ls < 5; ++ls) {
        const int s  = 1 << (2 * ls);
        const int os = s + (s >> 4);
        const float* Xr = sre[src];
        const float* Xi = sim[src];
        float*       Yr = sre[src ^ 1];
        float*       Yi = sim[src ^ 1];
        #pragma unroll
        for (int u = 0; u < 2; ++u) {
            int idx = tid + 256 * u;          // [0,512)
            int sp  = idx & ~(s - 1);         // s * p'
            int wi  = WIDX(idx);
            float a0r = Xr[wi],        a0i = Xi[wi];
            float a1r = Xr[wi + 544],  a1i = Xi[wi + 544];
            float a2r = Xr[wi + 1088], a2i = Xi[wi + 1088];
            float a3r = Xr[wi + 1632], a3i = Xi[wi + 1632];
            float t0r = a0r + a2r, t0i = a0i + a2i;
            float t1r = a0r - a2r, t1i = a0i - a2i;
            float t2r = a1r + a3r, t2i = a1i + a3i;
            float t3r = a1r - a3r, t3i = a1i - a3i;
            float y0r = t0r + t2r, y0i = t0i + t2i;
            float y1r = t1r + t3i, y1i = t1i - t3r;   // t1 - j t3
            float y2r = t0r - t2r, y2i = t0i - t2i;
            float y3r = t1r - t3i, y3i = t1i + t3r;   // t1 + j t3
            float2 w1 = tw[sp];
            float2 w2 = tw[2 * sp];
            float2 w3 = tw[3 * sp];
            int wo = WIDX(idx + 3 * sp);
            Yr[wo]          = y0r;
            Yi[wo]          = y0i;
            Yr[wo + os]     = y1r * w1.x - y1i * w1.y;
            Yi[wo + os]     = y1r * w1.y + y1i * w1.x;
            Yr[wo + 2 * os] = y2r * w2.x - y2i * w2.y;
            Yi[wo + 2 * os] = y2r * w2.y + y2i * w2.x;
            Yr[wo + 3 * os] = y3r * w3.x - y3i * w3.y;
            Yi[wo + 3 * os] = y3r * w3.y + y3i * w3.x;
        }
        __syncthreads();
        src ^= 1;
    }

    // ---- final radix-2 stage (twiddle=1) folded into unpack ----
    // Z[m] = m<1024 ? X5[m] + X5[m+1024] : X5[m-1024] - X5[m]
    // padded offset for +1024 is +1088.
    const float* Xr = sre[src];
    const float* Xi = sim[src];
    float2* scA = sc + ((size_t)b * FRAMES + fA) * KS;
    float2* scB = sc + ((size_t)b * FRAMES + fB) * KS;
    #pragma unroll
    for (int j = 0; j < 5; ++j) {
        int k = tid + 256 * j;
        if (k <= 1024) {
            int m2 = (2048 - k) & 2047;
            float u0r, u0i, v0r, v0i;
            // zk = Z(k)
            if (k < 1024) {
                int wa = WIDX(k);
                u0r = Xr[wa] + Xr[wa + 1088];
                u0i = Xi[wa] + Xi[wa + 1088];
            } else {
                u0r = Xr[0] - Xr[1088];
                u0i = Xi[0] - Xi[1088];
            }
            // zm = Z(m2)
            if (m2 < 1024) {
                int wa = WIDX(m2);
                v0r = Xr[wa] + Xr[wa + 1088];
                v0i = Xi[wa] + Xi[wa + 1088];
            } else {
                int wa = WIDX(m2 - 1024);
                v0r = Xr[wa] - Xr[wa + 1088];
                v0i = Xi[wa] - Xi[wa + 1088];
            }
            // A = (zk + conj(zm))/2 ; B = -i/2 (zk - conj(zm))
            float2 A = make_float2(0.5f * (u0r + v0r), 0.5f * (u0i - v0i));
            float2 B = make_float2(0.5f * (u0i + v0i), 0.5f * (v0r - u0r));
            scA[k] = A;
            if (hasB) scB[k] = B;
        }
    }
}

// Tile transpose: sc[b][f][k] -> out[b][k][t] (+ conjugate mirror rows).
// SoA tiles with odd word stride (65) -> conflict-free column reads.
__global__ __launch_bounds__(256) void transpose_out(
    const float2* __restrict__ sc, float* __restrict__ out)
{
    __shared__ float tre[64][65];
    __shared__ float tim[64][65];

    const int b  = blockIdx.x;   // 16
    const int kt = blockIdx.y;   // 17 tiles of 64 covering k=0..1024
    const int ft = blockIdx.z;   // 9 chunks of 64 covering f=0..512
    const int k0 = kt * 64;
    const int f0 = ft * 64;
    const int tid = threadIdx.x;

    #pragma unroll
    for (int i = 0; i < 16; ++i) {
        int idx = tid + 256 * i;
        int fl = idx >> 6, kl = idx & 63;
        int f = f0 + fl, k = k0 + kl;
        float2 v = make_float2(0.f, 0.f);
        if (f < FRAMES && k <= 1024)
            v = sc[((size_t)b * FRAMES + f) * KS + k];
        tre[fl][kl] = v.x;
        tim[fl][kl] = v.y;
    }
    __syncthreads();

    const int wave = tid >> 6, lane = tid & 63;
    const int t = f0 + lane;
    const bool tok = (t < FRAMES);
    float* o0 = out + (size_t)b * ((size_t)N_FFT * FRAMES);
    float* o1 = out + OHALF + (size_t)b * ((size_t)N_FFT * FRAMES);

    for (int kl = wave; kl < 64; kl += 4) {
        int k = k0 + kl;
        if (k > 1024) continue;
        float vr = tre[lane][kl];
        float vi = tim[lane][kl];
        if (tok) {
            o0[(size_t)k * FRAMES + t] = vr;
            o1[(size_t)k * FRAMES + t] = vi;
            if (k >= 1 && k <= 1023) {
                o0[(size_t)(N_FFT - k) * FRAMES + t] = vr;
                o1[(size_t)(N_FFT - k) * FRAMES + t] = -vi;
            }
        }
    }
}

// ===================== fallback: naive =====================================

__global__ void dft_naive(const float* __restrict__ x,
                          const float* __restrict__ wsin,
                          const float* __restrict__ wcos,
                          float* __restrict__ out)
{
    size_t i = (size_t)blockIdx.x * 256 + threadIdx.x;
    if (i >= OHALF) return;
    int t = (int)(i % FRAMES);
    size_t r = i / FRAMES;
    int k = (int)(r % N_FFT);
    int b = (int)(r / N_FFT);
    float sr = 0.f, si = 0.f;
    int base = t * HOP - N_FFT / 2;
    for (int n = 0; n < N_FFT; ++n) {
        int j = base + n;
        j = (j < 0) ? -j : ((j >= LENGTH) ? (2 * LENGTH - 2 - j) : j);
        float xv = x[(size_t)b * LENGTH + j];
        sr += xv * wcos[(size_t)k * N_FFT + n];
        si += xv * wsin[(size_t)k * N_FFT + n];
    }
    out[i] = sr;
    out[OHALF + i] = -si;
}

// ------------------------------- launch ------------------------------------

extern "C" void kernel_launch(void* const* d_in, const int* in_sizes, int n_in,
                              void* d_out, int out_size, void* d_ws, size_t ws_size,
                              hipStream_t stream) {
    const float* x    = (const float*)d_in[0];
    const float* wsin = (const float*)d_in[1];
    const float* wcos = (const float*)d_in[2];
    float* out = (float*)d_out;

    const size_t sc_f2   = (size_t)BATCH * FRAMES * KS;     // 8,421,408 float2
    const size_t need_ft = 24576 + sc_f2 * sizeof(float2);  // ~67.4 MB
    if (ws_size >= need_ft) {
        float2* tw  = (float2*)d_ws;                         // 2048 * 8 B
        float*  win = (float*)((char*)d_ws + 16384);         // 2048 * 4 B
        float2* sc  = (float2*)((char*)d_ws + 24576);
        init_tables<<<8, 256, 0, stream>>>(tw, win);
        fft_pairs<<<dim3(PAIRS, BATCH), 256, 0, stream>>>(x, tw, win, sc);
        transpose_out<<<dim3(BATCH, 17, 9), 256, 0, stream>>>(sc, out);
        return;
    }

    dft_naive<<<(int)((OHALF + 255) / 256), 256, 0, stream>>>(x, wsin, wcos, out);
}

// Round 2
// 252.879 us; speedup vs baseline: 1.0387x; 1.0022x over previous
//
#include <hip/hip_runtime.h>
#include <stdint.h>
#include <math.h>

// ---------------------------------------------------------------------------
// DFT_12223476924859: STFT via batched real-pair FFT (memory-bound).
//   out0[b,k,t] = Re X_t[k], out1[b,k,t] = Im X_t[k],  X_t = FFT(win*frame_t)
// Two real frames packed per complex 2048-pt FFT. Stockham radix-4 DIF:
// 5 stages (s=1,4,16,64,256) + final radix-2 (twiddle=1) folded into the
// conjugate-symmetric unpack. 6 barriers total.
//
// R2 (this round): AoS float2 LDS + pad swizzle in float2 units.
//   R1's SoA split fixed bank conflicts but forced all LDS traffic to
//   scalar ds_read_b32/ds_write_b32 (~184 ops/thread, ~44 B/cyc). AoS
//   float2 emits ds_*_b64 (~98 ops/thread, ~75-85 B/cyc) while the pad
//   swizzle W(w)=w+(w>>4) (float2 units) keeps stage writes conflict-free:
//   verified per stage that W(o+m*s)=W(o)+m*os with os=s+(s>>4)
//   (m-runs never cross a 16-boundary for s=1,4; cross exactly for
//   s=16,64,256). Reads: W(idx+512m)=W(idx)+544m; unpack partner +1088.
//  - transpose_out keeps R1's SoA float[64][65] tiles (conflict-free).
//  - interior pairs (p in [1,254]: no reflect) load x/win as float4.
// Harness fills (~105us re-poison) are fixed overhead outside our control.
// ---------------------------------------------------------------------------

#define N_FFT   2048
#define HOP     512
#define BATCH   16
#define LENGTH  262144
#define FRAMES  513
#define OHALF   ((size_t)BATCH * N_FFT * FRAMES)  // 16,809,984
#define KS      1026                      // per-frame float2 stride in scratch
#define PAIRS   257                       // ceil(513/2)

// padded LDS index (float2 units): 1 pad slot per 16.
#define WIDX(w) ((w) + ((w) >> 4))
#define LDSN    2176                      // WIDX(2047)=2174, rounded up

__device__ __forceinline__ float2 cmul(float2 a, float2 w) {
    return make_float2(a.x * w.x - a.y * w.y, a.x * w.y + a.y * w.x);
}

// ============================ FFT path =====================================

__global__ void init_tables(float2* __restrict__ tw, float* __restrict__ win) {
    int i = blockIdx.x * 256 + threadIdx.x;   // grid covers 0..2047
    if (i < 2048) {
        double a = -2.0 * M_PI * (double)i / 2048.0;
        tw[i] = make_float2((float)cos(a), (float)sin(a));
        double aw = 2.0 * M_PI * (double)i / 2048.0;
        win[i] = (float)(0.5 - 0.5 * cos(aw));
    }
}

// One block = one pair of frames (2p, 2p+1) of one batch.
// z = wxA + i*wxB; Stockham radix-4, LDS ping-pong (AoS float2 + pad
// swizzle), natural-order output.
__global__ __launch_bounds__(256) void fft_pairs(
    const float* __restrict__ x, const float2* __restrict__ tw,
    const float* __restrict__ win, float2* __restrict__ sc)
{
    __shared__ float2 buf[2][LDSN];   // ~34.8 KB ping-pong

    const int tid = threadIdx.x;
    const int p   = blockIdx.x;       // pair index 0..256
    const int b   = blockIdx.y;
    const int fA  = 2 * p;
    const int fB  = 2 * p + 1;
    const bool hasB = (fB < FRAMES);
    const float* xb = x + (size_t)b * LENGTH;

    // ---- load windowed frames ----
    if (p >= 1 && p <= 254) {
        // interior: no reflect on either frame; bases 16B-aligned
        const float4* xA = (const float4*)(xb + fA * HOP - (N_FFT / 2));
        const float4* xB = (const float4*)(xb + fB * HOP - (N_FFT / 2));
        const float4* w4 = (const float4*)win;
        #pragma unroll
        for (int j = 0; j < 2; ++j) {
            int q = tid + 256 * j;            // float4 index, covers 2048 floats
            float4 wv = w4[q];
            float4 va = xA[q];
            float4 vb = xB[q];
            int wn = 4 * q + (q >> 2);        // = WIDX(4q); run of 4 stays in block
            buf[0][wn + 0] = make_float2(va.x * wv.x, vb.x * wv.x);
            buf[0][wn + 1] = make_float2(va.y * wv.y, vb.y * wv.y);
            buf[0][wn + 2] = make_float2(va.z * wv.z, vb.z * wv.z);
            buf[0][wn + 3] = make_float2(va.w * wv.w, vb.w * wv.w);
        }
    } else {
        // boundary pairs (p=0,255,256): reflect padding, scalar path
        #pragma unroll
        for (int j = 0; j < 8; ++j) {
            int n = tid + 256 * j;
            float w = win[n];
            int ja = fA * HOP + n - (N_FFT / 2);
            ja = (ja < 0) ? -ja : ((ja >= LENGTH) ? 2 * LENGTH - 2 - ja : ja);
            float va = xb[ja] * w;
            float vb = 0.f;
            if (hasB) {
                int jb = fB * HOP + n - (N_FFT / 2);
                jb = (jb < 0) ? -jb : ((jb >= LENGTH) ? 2 * LENGTH - 2 - jb : jb);
                vb = xb[jb] * w;
            }
            buf[0][WIDX(n)] = make_float2(va, vb);
        }
    }
    __syncthreads();

    // ---- 5 Stockham radix-4 DIF stages: s = 1,4,16,64,256 ----
    // butterfly idx in [0,512): sp = idx & ~(s-1) (= s*p')
    //   a_m = X[idx + m*512];  Z[idx + 3*sp + m*s] = tw[m*sp] * DFT4(a)[m]
    // padded-space (f2 units): read m-step 544; write m-step os=s+(s>>4).
    int src = 0;
    #pragma unroll
    for (int ls = 0; ls < 5; ++ls) {
        const int s  = 1 << (2 * ls);
        const int os = s + (s >> 4);
        const float2* X = buf[src];
        float2*       Y = buf[src ^ 1];
        #pragma unroll
        for (int u = 0; u < 2; ++u) {
            int idx = tid + 256 * u;          // [0,512)
            int sp  = idx & ~(s - 1);         // s * p'
            int wi  = WIDX(idx);
            float2 a0 = X[wi];
            float2 a1 = X[wi + 544];
            float2 a2 = X[wi + 1088];
            float2 a3 = X[wi + 1632];
            float2 t0 = make_float2(a0.x + a2.x, a0.y + a2.y);
            float2 t1 = make_float2(a0.x - a2.x, a0.y - a2.y);
            float2 t2 = make_float2(a1.x + a3.x, a1.y + a3.y);
            float2 t3 = make_float2(a1.x - a3.x, a1.y - a3.y);
            float2 y0 = make_float2(t0.x + t2.x, t0.y + t2.y);
            float2 y1 = make_float2(t1.x + t3.y, t1.y - t3.x);   // t1 - j t3
            float2 y2 = make_float2(t0.x - t2.x, t0.y - t2.y);
            float2 y3 = make_float2(t1.x - t3.y, t1.y + t3.x);   // t1 + j t3
            float2 w1 = tw[sp];
            float2 w2 = tw[2 * sp];
            float2 w3 = tw[3 * sp];
            int wo = WIDX(idx + 3 * sp);
            Y[wo]          = y0;
            Y[wo + os]     = cmul(y1, w1);
            Y[wo + 2 * os] = cmul(y2, w2);
            Y[wo + 3 * os] = cmul(y3, w3);
        }
        __syncthreads();
        src ^= 1;
    }

    // ---- final radix-2 stage (twiddle=1) folded into unpack ----
    // Z[m] = m<1024 ? X5[m] + X5[m+1024] : X5[m-1024] - X5[m]
    // padded offset for +1024 is +1088 (f2 units).
    const float2* X5 = buf[src];
    float2* scA = sc + ((size_t)b * FRAMES + fA) * KS;
    float2* scB = sc + ((size_t)b * FRAMES + fB) * KS;
    #pragma unroll
    for (int j = 0; j < 5; ++j) {
        int k = tid + 256 * j;
        if (k <= 1024) {
            int m2 = (2048 - k) & 2047;
            float2 u0, u1, v0, v1;
            // zk = Z(k)
            if (k < 1024) {
                int wa = WIDX(k);
                u0 = X5[wa]; u1 = X5[wa + 1088];
                u0 = make_float2(u0.x + u1.x, u0.y + u1.y);
            } else {
                u0 = X5[0]; u1 = X5[1088];
                u0 = make_float2(u0.x - u1.x, u0.y - u1.y);
            }
            // zm = Z(m2)
            if (m2 < 1024) {
                int wa = WIDX(m2);
                v0 = X5[wa]; v1 = X5[wa + 1088];
                v0 = make_float2(v0.x + v1.x, v0.y + v1.y);
            } else {
                int wa = WIDX(m2 - 1024);
                v0 = X5[wa]; v1 = X5[wa + 1088];
                v0 = make_float2(v0.x - v1.x, v0.y - v1.y);
            }
            // A = (zk + conj(zm))/2 ; B = -i/2 (zk - conj(zm))
            float2 A = make_float2(0.5f * (u0.x + v0.x), 0.5f * (u0.y - v0.y));
            float2 B = make_float2(0.5f * (u0.y + v0.y), 0.5f * (v0.x - u0.x));
            scA[k] = A;
            if (hasB) scB[k] = B;
        }
    }
}

// Tile transpose: sc[b][f][k] -> out[b][k][t] (+ conjugate mirror rows).
// SoA tiles with odd word stride (65) -> conflict-free column reads.
__global__ __launch_bounds__(256) void transpose_out(
    const float2* __restrict__ sc, float* __restrict__ out)
{
    __shared__ float tre[64][65];
    __shared__ float tim[64][65];

    const int b  = blockIdx.x;   // 16
    const int kt = blockIdx.y;   // 17 tiles of 64 covering k=0..1024
    const int ft = blockIdx.z;   // 9 chunks of 64 covering f=0..512
    const int k0 = kt * 64;
    const int f0 = ft * 64;
    const int tid = threadIdx.x;

    #pragma unroll
    for (int i = 0; i < 16; ++i) {
        int idx = tid + 256 * i;
        int fl = idx >> 6, kl = idx & 63;
        int f = f0 + fl, k = k0 + kl;
        float2 v = make_float2(0.f, 0.f);
        if (f < FRAMES && k <= 1024)
            v = sc[((size_t)b * FRAMES + f) * KS + k];
        tre[fl][kl] = v.x;
        tim[fl][kl] = v.y;
    }
    __syncthreads();

    const int wave = tid >> 6, lane = tid & 63;
    const int t = f0 + lane;
    const bool tok = (t < FRAMES);
    float* o0 = out + (size_t)b * ((size_t)N_FFT * FRAMES);
    float* o1 = out + OHALF + (size_t)b * ((size_t)N_FFT * FRAMES);

    for (int kl = wave; kl < 64; kl += 4) {
        int k = k0 + kl;
        if (k > 1024) continue;
        float vr = tre[lane][kl];
        float vi = tim[lane][kl];
        if (tok) {
            o0[(size_t)k * FRAMES + t] = vr;
            o1[(size_t)k * FRAMES + t] = vi;
            if (k >= 1 && k <= 1023) {
                o0[(size_t)(N_FFT - k) * FRAMES + t] = vr;
                o1[(size_t)(N_FFT - k) * FRAMES + t] = -vi;
            }
        }
    }
}

// ===================== fallback: naive =====================================

__global__ void dft_naive(const float* __restrict__ x,
                          const float* __restrict__ wsin,
                          const float* __restrict__ wcos,
                          float* __restrict__ out)
{
    size_t i = (size_t)blockIdx.x * 256 + threadIdx.x;
    if (i >= OHALF) return;
    int t = (int)(i % FRAMES);
    size_t r = i / FRAMES;
    int k = (int)(r % N_FFT);
    int b = (int)(r / N_FFT);
    float sr = 0.f, si = 0.f;
    int base = t * HOP - N_FFT / 2;
    for (int n = 0; n < N_FFT; ++n) {
        int j = base + n;
        j = (j < 0) ? -j : ((j >= LENGTH) ? (2 * LENGTH - 2 - j) : j);
        float xv = x[(size_t)b * LENGTH + j];
        sr += xv * wcos[(size_t)k * N_FFT + n];
        si += xv * wsin[(size_t)k * N_FFT + n];
    }
    out[i] = sr;
    out[OHALF + i] = -si;
}

// ------------------------------- launch ------------------------------------

extern "C" void kernel_launch(void* const* d_in, const int* in_sizes, int n_in,
                              void* d_out, int out_size, void* d_ws, size_t ws_size,
                              hipStream_t stream) {
    const float* x    = (const float*)d_in[0];
    const float* wsin = (const float*)d_in[1];
    const float* wcos = (const float*)d_in[2];
    float* out = (float*)d_out;

    const size_t sc_f2   = (size_t)BATCH * FRAMES * KS;     // 8,421,408 float2
    const size_t need_ft = 24576 + sc_f2 * sizeof(float2);  // ~67.4 MB
    if (ws_size >= need_ft) {
        float2* tw  = (float2*)d_ws;                         // 2048 * 8 B
        float*  win = (float*)((char*)d_ws + 16384);         // 2048 * 4 B
        float2* sc  = (float2*)((char*)d_ws + 24576);
        init_tables<<<8, 256, 0, stream>>>(tw, win);
        fft_pairs<<<dim3(PAIRS, BATCH), 256, 0, stream>>>(x, tw, win, sc);
        transpose_out<<<dim3(BATCH, 17, 9), 256, 0, stream>>>(sc, out);
        return;
    }

    dft_naive<<<(int)((OHALF + 255) / 256), 256, 0, stream>>>(x, wsin, wcos, out);
}

// Round 3
// 245.429 us; speedup vs baseline: 1.0702x; 1.0304x over previous
//
#include <hip/hip_runtime.h>
#include <stdint.h>
#include <math.h>

// ---------------------------------------------------------------------------
// DFT_12223476924859: STFT via batched real-pair FFT (memory-bound).
//   out0[b,k,t] = Re X_t[k], out1[b,k,t] = Im X_t[k],  X_t = FFT(win*frame_t)
// Two real frames packed per complex 2048-pt FFT. Stockham radix-4 DIF:
// 5 stages (s=1,4,16,64,256) + final radix-2 (twiddle=1) folded into the
// conjugate-symmetric unpack.
//
// R3 (this round): kill global twiddle/window loads + fuse stage 1.
//  - Twiddles computed in-register via __sincosf: w1=(c,-s), w2=w1^2,
//    w3=w1*w2. Replaces ~30 dependent global loads per thread (L2 latency
//    ~200cy each, barrier-locked phases couldn't hide them) with pure ALU.
//  - Stage 1 fused with the load: x -> registers -> butterfly -> LDS.
//    One sincos of theta=2*pi*idx/2048 yields BOTH the 4 Hann window taps
//    (quadrant identities for cos(theta+m*pi/2)) and the stage-1 twiddle.
//    Removes the input LDS round-trip (16 b64 ops) and one barrier (6->5).
//  - init_tables kernel dropped entirely (no tables).
//  - Keeps R1/R2: pad-swizzled AoS float2 LDS (W(w)=w+(w>>4), os=s+(s>>4)),
//    SoA float[64][65] transpose tiles (all conflict-free).
// Harness fills (~105us re-poison) are fixed overhead outside our control.
// ---------------------------------------------------------------------------

#define N_FFT   2048
#define HOP     512
#define BATCH   16
#define LENGTH  262144
#define FRAMES  513
#define OHALF   ((size_t)BATCH * N_FFT * FRAMES)  // 16,809,984
#define KS      1026                      // per-frame float2 stride in scratch
#define PAIRS   257                       // ceil(513/2)

// padded LDS index (float2 units): 1 pad slot per 16.
#define WIDX(w) ((w) + ((w) >> 4))
#define LDSN    2176                      // WIDX(2047)=2174, rounded up

#define TWO_PI_OVER_N  3.0679615757712823e-3f   // 2*pi/2048

__device__ __forceinline__ float2 cmul(float2 a, float2 w) {
    return make_float2(a.x * w.x - a.y * w.y, a.x * w.y + a.y * w.x);
}
__device__ __forceinline__ float2 csq(float2 w) {
    return make_float2(w.x * w.x - w.y * w.y, 2.f * w.x * w.y);
}

// ============================ FFT path =====================================

// One block = one pair of frames (2p, 2p+1) of one batch.
// z = wxA + i*wxB; Stockham radix-4, LDS ping-pong (AoS float2 + pad
// swizzle), natural-order output. Twiddles & window via hw sincos.
__global__ __launch_bounds__(256) void fft_pairs(
    const float* __restrict__ x, float2* __restrict__ sc)
{
    __shared__ float2 buf[2][LDSN];   // ~34.8 KB ping-pong

    const int tid = threadIdx.x;
    const int p   = blockIdx.x;       // pair index 0..256
    const int b   = blockIdx.y;
    const int fA  = 2 * p;
    const int fB  = 2 * p + 1;
    const bool hasB = (fB < FRAMES);
    const float* xb = x + (size_t)b * LENGTH;
    const bool interior = (p >= 1 && p <= 254);

    // ---- fused: load + window + stage-1 (s=1) radix-4 butterfly ----
    // a_m = win(idx+512m) * x(idx+512m);  Z[4*idx+m] = w1^m * DFT4(a)_m
    // win(n) = 0.5 - 0.5*cos(2*pi*n/2048); for n = idx+512m the cosines are
    // {c, -s, -c, s} with (s,c) = sincos(2*pi*idx/2048). w1 = (c, -s).
    {
        const int baseA = fA * HOP - (N_FFT / 2);
        const int baseB = fB * HOP - (N_FFT / 2);
        #pragma unroll
        for (int u = 0; u < 2; ++u) {
            int idx = tid + 256 * u;          // [0,512)
            float sn, cs;
            __sincosf((float)idx * TWO_PI_OVER_N, &sn, &cs);
            float w0 = 0.5f - 0.5f * cs;
            float w1v = 0.5f + 0.5f * sn;
            float w2v = 0.5f + 0.5f * cs;
            float w3v = 0.5f - 0.5f * sn;

            float xa0, xa1, xa2, xa3, xb0, xb1, xb2, xb3;
            if (interior) {
                xa0 = xb[baseA + idx];
                xa1 = xb[baseA + idx + 512];
                xa2 = xb[baseA + idx + 1024];
                xa3 = xb[baseA + idx + 1536];
                xb0 = xb[baseB + idx];
                xb1 = xb[baseB + idx + 512];
                xb2 = xb[baseB + idx + 1024];
                xb3 = xb[baseB + idx + 1536];
            } else {
                #pragma unroll
                for (int m = 0; m < 4; ++m) {
                    int ja = baseA + idx + 512 * m;
                    ja = (ja < 0) ? -ja : ((ja >= LENGTH) ? 2 * LENGTH - 2 - ja : ja);
                    float va = xb[ja];
                    float vb = 0.f;
                    if (hasB) {
                        int jb = baseB + idx + 512 * m;
                        jb = (jb < 0) ? -jb : ((jb >= LENGTH) ? 2 * LENGTH - 2 - jb : jb);
                        vb = xb[jb];
                    }
                    if (m == 0) { xa0 = va; xb0 = vb; }
                    else if (m == 1) { xa1 = va; xb1 = vb; }
                    else if (m == 2) { xa2 = va; xb2 = vb; }
                    else { xa3 = va; xb3 = vb; }
                }
            }

            float2 a0 = make_float2(xa0 * w0, xb0 * w0);
            float2 a1 = make_float2(xa1 * w1v, xb1 * w1v);
            float2 a2 = make_float2(xa2 * w2v, xb2 * w2v);
            float2 a3 = make_float2(xa3 * w3v, xb3 * w3v);

            float2 t0 = make_float2(a0.x + a2.x, a0.y + a2.y);
            float2 t1 = make_float2(a0.x - a2.x, a0.y - a2.y);
            float2 t2 = make_float2(a1.x + a3.x, a1.y + a3.y);
            float2 t3 = make_float2(a1.x - a3.x, a1.y - a3.y);
            float2 y0 = make_float2(t0.x + t2.x, t0.y + t2.y);
            float2 y1 = make_float2(t1.x + t3.y, t1.y - t3.x);   // t1 - j t3
            float2 y2 = make_float2(t0.x - t2.x, t0.y - t2.y);
            float2 y3 = make_float2(t1.x - t3.y, t1.y + t3.x);   // t1 + j t3

            float2 tw1 = make_float2(cs, -sn);
            float2 tw2 = csq(tw1);
            float2 tw3 = cmul(tw1, tw2);

            int wo = WIDX(4 * idx);           // run of 4 stays in 16-block
            buf[0][wo]     = y0;
            buf[0][wo + 1] = cmul(y1, tw1);
            buf[0][wo + 2] = cmul(y2, tw2);
            buf[0][wo + 3] = cmul(y3, tw3);
        }
    }
    __syncthreads();

    // ---- remaining Stockham radix-4 DIF stages: s = 4,16,64,256 ----
    // butterfly idx in [0,512): sp = idx & ~(s-1) (= s*p')
    //   a_m = X[idx + m*512];  Z[idx + 3*sp + m*s] = w1^m * DFT4(a)_m
    // padded-space (f2 units): read m-step 544; write m-step os=s+(s>>4).
    int src = 0;
    #pragma unroll
    for (int ls = 1; ls < 5; ++ls) {
        const int s  = 1 << (2 * ls);
        const int os = s + (s >> 4);
        const float2* X = buf[src];
        float2*       Y = buf[src ^ 1];
        #pragma unroll
        for (int u = 0; u < 2; ++u) {
            int idx = tid + 256 * u;          // [0,512)
            int sp  = idx & ~(s - 1);         // s * p'
            int wi  = WIDX(idx);
            float2 a0 = X[wi];
            float2 a1 = X[wi + 544];
            float2 a2 = X[wi + 1088];
            float2 a3 = X[wi + 1632];

            float sn, cs;
            __sincosf((float)sp * TWO_PI_OVER_N, &sn, &cs);
            float2 w1 = make_float2(cs, -sn);
            float2 w2 = csq(w1);
            float2 w3 = cmul(w1, w2);

            float2 t0 = make_float2(a0.x + a2.x, a0.y + a2.y);
            float2 t1 = make_float2(a0.x - a2.x, a0.y - a2.y);
            float2 t2 = make_float2(a1.x + a3.x, a1.y + a3.y);
            float2 t3 = make_float2(a1.x - a3.x, a1.y - a3.y);
            float2 y0 = make_float2(t0.x + t2.x, t0.y + t2.y);
            float2 y1 = make_float2(t1.x + t3.y, t1.y - t3.x);   // t1 - j t3
            float2 y2 = make_float2(t0.x - t2.x, t0.y - t2.y);
            float2 y3 = make_float2(t1.x - t3.y, t1.y + t3.x);   // t1 + j t3

            int wo = WIDX(idx + 3 * sp);
            Y[wo]          = y0;
            Y[wo + os]     = cmul(y1, w1);
            Y[wo + 2 * os] = cmul(y2, w2);
            Y[wo + 3 * os] = cmul(y3, w3);
        }
        __syncthreads();
        src ^= 1;
    }

    // ---- final radix-2 stage (twiddle=1) folded into unpack ----
    // Z[m] = m<1024 ? X5[m] + X5[m+1024] : X5[m-1024] - X5[m]
    // padded offset for +1024 is +1088 (f2 units).
    const float2* X5 = buf[src];
    float2* scA = sc + ((size_t)b * FRAMES + fA) * KS;
    float2* scB = sc + ((size_t)b * FRAMES + fB) * KS;
    #pragma unroll
    for (int j = 0; j < 5; ++j) {
        int k = tid + 256 * j;
        if (k <= 1024) {
            int m2 = (2048 - k) & 2047;
            float2 u0, u1, v0, v1;
            // zk = Z(k)
            if (k < 1024) {
                int wa = WIDX(k);
                u0 = X5[wa]; u1 = X5[wa + 1088];
                u0 = make_float2(u0.x + u1.x, u0.y + u1.y);
            } else {
                u0 = X5[0]; u1 = X5[1088];
                u0 = make_float2(u0.x - u1.x, u0.y - u1.y);
            }
            // zm = Z(m2)
            if (m2 < 1024) {
                int wa = WIDX(m2);
                v0 = X5[wa]; v1 = X5[wa + 1088];
                v0 = make_float2(v0.x + v1.x, v0.y + v1.y);
            } else {
                int wa = WIDX(m2 - 1024);
                v0 = X5[wa]; v1 = X5[wa + 1088];
                v0 = make_float2(v0.x - v1.x, v0.y - v1.y);
            }
            // A = (zk + conj(zm))/2 ; B = -i/2 (zk - conj(zm))
            float2 A = make_float2(0.5f * (u0.x + v0.x), 0.5f * (u0.y - v0.y));
            float2 B = make_float2(0.5f * (u0.y + v0.y), 0.5f * (v0.x - u0.x));
            scA[k] = A;
            if (hasB) scB[k] = B;
        }
    }
}

// Tile transpose: sc[b][f][k] -> out[b][k][t] (+ conjugate mirror rows).
// SoA tiles with odd word stride (65) -> conflict-free column reads.
__global__ __launch_bounds__(256) void transpose_out(
    const float2* __restrict__ sc, float* __restrict__ out)
{
    __shared__ float tre[64][65];
    __shared__ float tim[64][65];

    const int b  = blockIdx.x;   // 16
    const int kt = blockIdx.y;   // 17 tiles of 64 covering k=0..1024
    const int ft = blockIdx.z;   // 9 chunks of 64 covering f=0..512
    const int k0 = kt * 64;
    const int f0 = ft * 64;
    const int tid = threadIdx.x;

    #pragma unroll
    for (int i = 0; i < 16; ++i) {
        int idx = tid + 256 * i;
        int fl = idx >> 6, kl = idx & 63;
        int f = f0 + fl, k = k0 + kl;
        float2 v = make_float2(0.f, 0.f);
        if (f < FRAMES && k <= 1024)
            v = sc[((size_t)b * FRAMES + f) * KS + k];
        tre[fl][kl] = v.x;
        tim[fl][kl] = v.y;
    }
    __syncthreads();

    const int wave = tid >> 6, lane = tid & 63;
    const int t = f0 + lane;
    const bool tok = (t < FRAMES);
    float* o0 = out + (size_t)b * ((size_t)N_FFT * FRAMES);
    float* o1 = out + OHALF + (size_t)b * ((size_t)N_FFT * FRAMES);

    for (int kl = wave; kl < 64; kl += 4) {
        int k = k0 + kl;
        if (k > 1024) continue;
        float vr = tre[lane][kl];
        float vi = tim[lane][kl];
        if (tok) {
            o0[(size_t)k * FRAMES + t] = vr;
            o1[(size_t)k * FRAMES + t] = vi;
            if (k >= 1 && k <= 1023) {
                o0[(size_t)(N_FFT - k) * FRAMES + t] = vr;
                o1[(size_t)(N_FFT - k) * FRAMES + t] = -vi;
            }
        }
    }
}

// ===================== fallback: naive =====================================

__global__ void dft_naive(const float* __restrict__ x,
                          const float* __restrict__ wsin,
                          const float* __restrict__ wcos,
                          float* __restrict__ out)
{
    size_t i = (size_t)blockIdx.x * 256 + threadIdx.x;
    if (i >= OHALF) return;
    int t = (int)(i % FRAMES);
    size_t r = i / FRAMES;
    int k = (int)(r % N_FFT);
    int b = (int)(r / N_FFT);
    float sr = 0.f, si = 0.f;
    int base = t * HOP - N_FFT / 2;
    for (int n = 0; n < N_FFT; ++n) {
        int j = base + n;
        j = (j < 0) ? -j : ((j >= LENGTH) ? (2 * LENGTH - 2 - j) : j);
        float xv = x[(size_t)b * LENGTH + j];
        sr += xv * wcos[(size_t)k * N_FFT + n];
        si += xv * wsin[(size_t)k * N_FFT + n];
    }
    out[i] = sr;
    out[OHALF + i] = -si;
}

// ------------------------------- launch ------------------------------------

extern "C" void kernel_launch(void* const* d_in, const int* in_sizes, int n_in,
                              void* d_out, int out_size, void* d_ws, size_t ws_size,
                              hipStream_t stream) {
    const float* x    = (const float*)d_in[0];
    const float* wsin = (const float*)d_in[1];
    const float* wcos = (const float*)d_in[2];
    float* out = (float*)d_out;

    const size_t sc_f2   = (size_t)BATCH * FRAMES * KS;     // 8,421,408 float2
    const size_t need_ft = sc_f2 * sizeof(float2);          // ~67.4 MB
    if (ws_size >= need_ft) {
        float2* sc = (float2*)d_ws;
        fft_pairs<<<dim3(PAIRS, BATCH), 256, 0, stream>>>(x, sc);
        transpose_out<<<dim3(BATCH, 17, 9), 256, 0, stream>>>(sc, out);
        return;
    }

    dft_naive<<<(int)((OHALF + 255) / 256), 256, 0, stream>>>(x, wsin, wcos, out);
}